// Round 5
// baseline (206.547 us; speedup 1.0000x reference)
//
#include <hip/hip_runtime.h>

// Problem constants (fixed by setup_inputs): B=4, D=32, H=512, W=512, K=16
#define B_ 4
#define D_ 32
#define H_ 512
#define W_ 512
#define K_ 16
#define N_ (H_ * W_)    // 262144 pixels per image
#define NQ_ (N_ / 4)    // 65536 float4-quads per image
#define NBLK_ 256       // attract blocks per image (256 blk * 256 thr * 4 px = N_)
#define NTOT_ (NBLK_ * B_)
#define EPAD 33         // sE row pad: bank=(k*33+d)%32 distinct for distinct k

// Workspace layout (float indices). Cross-block data goes ONLY through
// device-scope atomics (coherent point) — no threadfence anywhere hot.
#define WS_CTR  192    // [1]   int completion counter (zeroed by zero_kernel)
#define WS_ASUM 256    // [64]  ull  scaled-int attract sums   (floats 256..383)
#define WS_ACNT 384    // [64]  uint attract counts            (floats 384..447)

#define SCALE_F 1073741824.0      // 2^30 (exact power-of-two scaling)
#define INV_SCALE 9.313225746154785e-10  // 2^-30

typedef float vfloat4 __attribute__((ext_vector_type(4)));
typedef int vint4 __attribute__((ext_vector_type(4)));

// Plain (cache-friendly) vector loads: the harness restore-copy leaves the
// input LLC-resident; nontemporal hints would forfeit those hits.
__device__ inline vfloat4 ld_f4(const float* p) { return *(const vfloat4*)p; }
__device__ inline vint4 ld_i4(const int* p) { return *(const vint4*)p; }

// Zero accumulators + counter (stream-ordered before attract_kernel; kernel
// dispatch boundaries provide the release so attract's atomics see zeros).
__global__ __launch_bounds__(64) void zero_kernel(float* __restrict__ ws) {
  const int t = threadIdx.x;
  ((unsigned long long*)(ws + WS_ASUM))[t] = 0ull;
  ((unsigned int*)(ws + WS_ACNT))[t] = 0u;
  if (t == 0) ((int*)ws)[WS_CTR] = 0;
}

// Single fused kernel: E gather + attract accumulation + last-block finalize.
__global__ __launch_bounds__(256) void attract_kernel(
    const float* __restrict__ outp, const int* __restrict__ target,
    const int* __restrict__ centers, float* __restrict__ ws,
    float* __restrict__ out) {
  const int b = blockIdx.y;
  const int tid = threadIdx.x;
  __shared__ float sE[K_ * EPAD];
  __shared__ float se2[K_];
  __shared__ int slab[K_];
  __shared__ int scy[K_], scx[K_];
  __shared__ float bs[K_];
  __shared__ float bc[K_];
  __shared__ int is_last;

  // --- Prologue: gather E/e2/labels directly from global (L2-hot; ~2.5 KB).
  if (tid < 2 * K_) {
    const int v = centers[b * (2 * K_) + tid];
    if (tid & 1) scx[tid >> 1] = v; else scy[tid >> 1] = v;
  }
  __syncthreads();
  {
    const int k = tid >> 4, d0 = tid & 15;           // 256 threads -> 2 elems each
    const size_t cbase = ((size_t)b * D_ * H_ + scy[k]) * W_ + scx[k];
    const float v0 = outp[cbase + (size_t)d0 * N_];
    const float v1 = outp[cbase + (size_t)(d0 + 16) * N_];
    sE[k * EPAD + d0] = v0;
    sE[k * EPAD + d0 + 16] = v1;
    float p = fmaf(v0, v0, v1 * v1);
#pragma unroll
    for (int off = 1; off < 16; off <<= 1) p += __shfl_xor(p, off, 64);
    if ((tid & 15) == 0) se2[k] = p;
    if (tid < K_) {
      slab[tid] = target[(size_t)b * N_ + scy[tid] * W_ + scx[tid]];
      bs[tid] = 0.0f;
      bc[tid] = 0.0f;
    }
  }
  __syncthreads();

  // --- Main loop: one float4-quad of pixels per thread.
  const int q = blockIdx.x * 256 + tid;  // [0, NQ_)
  const float* xb = outp + (size_t)b * D_ * N_;
  const vint4 lab4 = ld_i4(target + (size_t)b * N_ + 4 * q);
  const int labv[4] = {lab4.x, lab4.y, lab4.z, lab4.w};

  int kf[4], nm[4];
#pragma unroll
  for (int j = 0; j < 4; ++j) { kf[j] = 0; nm[j] = 0; }
#pragma unroll
  for (int k = 0; k < K_; ++k) {
    const int lk = slab[k];
#pragma unroll
    for (int j = 0; j < 4; ++j) {
      if (labv[j] == lk) { if (nm[j] == 0) kf[j] = k; nm[j]++; }
    }
  }

  float dot[4] = {0.f, 0.f, 0.f, 0.f};
  float x2[4] = {0.f, 0.f, 0.f, 0.f};
#pragma unroll
  for (int d = 0; d < D_; ++d) {
    const vfloat4 x = ld_f4(xb + (size_t)d * N_ + 4 * q);
    const float xs[4] = {x.x, x.y, x.z, x.w};
#pragma unroll
    for (int j = 0; j < 4; ++j) {
      const float e = sE[kf[j] * EPAD + d];
      dot[j] = fmaf(xs[j], e, dot[j]);
      x2[j] = fmaf(xs[j], xs[j], x2[j]);
    }
  }

  float hv[4];
#pragma unroll
  for (int j = 0; j < 4; ++j) {
    const float d2 = x2[j] + se2[kf[j]] - 2.0f * dot[j];
    const float h = fmaxf(sqrtf(fmaxf(d2, 0.0f)) - 0.1f, 0.0f);  // DELTA_A=0.1
    hv[j] = (nm[j] > 0) ? h : 0.0f;
  }

  // --- Epilogue: labels are constant over 128-pixel runs = 32-lane groups.
  const bool same = (kf[0] == kf[1]) & (kf[1] == kf[2]) & (kf[2] == kf[3]);
  float hsum = hv[0] + hv[1] + hv[2] + hv[3];
  float csum = (float)((nm[0] > 0) + (nm[1] > 0) + (nm[2] > 0) + (nm[3] > 0));
  int gi = same ? (kf[0] + 1) : 0;  // 0 = not uniform / invalid
#pragma unroll
  for (int off = 1; off < 32; off <<= 1) {
    const int o = __shfl_xor(gi, off, 64);
    if (o != gi) gi = 0;
  }
  if (gi != 0) {  // whole 32-lane group shares one k: one atomic per group
#pragma unroll
    for (int off = 1; off < 32; off <<= 1) {
      hsum += __shfl_xor(hsum, off, 64);
      csum += __shfl_xor(csum, off, 64);
    }
    if ((tid & 31) == 0 && csum > 0.0f) {
      atomicAdd(&bs[gi - 1], hsum);
      atomicAdd(&bc[gi - 1], csum);
    }
  } else if (same) {
    if (csum > 0.0f) {
      atomicAdd(&bs[kf[0]], hsum);
      atomicAdd(&bc[kf[0]], csum);
    }
  } else {
#pragma unroll
    for (int j = 0; j < 4; ++j) {
      if (nm[j] > 0) {
        atomicAdd(&bs[kf[j]], hv[j]);
        atomicAdd(&bc[kf[j]], 1.0f);
      }
    }
  }

  // Rare general case: duplicate-label centers (never taken on this input).
  const bool extra = (nm[0] > 1) | (nm[1] > 1) | (nm[2] > 1) | (nm[3] > 1);
  if (__any(extra)) {
    for (int k = 0; k < K_; ++k) {
      bool need[4]; bool anyn = false;
#pragma unroll
      for (int j = 0; j < 4; ++j) {
        need[j] = (nm[j] > 1) && (labv[j] == slab[k]) && (k != kf[j]);
        anyn |= need[j];
      }
      if (__any(anyn)) {
        float dt[4] = {0.f, 0.f, 0.f, 0.f};
        for (int d = 0; d < D_; ++d) {
          const vfloat4 x = ld_f4(xb + (size_t)d * N_ + 4 * q);
          const float e = sE[k * EPAD + d];
          dt[0] = fmaf(x.x, e, dt[0]);
          dt[1] = fmaf(x.y, e, dt[1]);
          dt[2] = fmaf(x.z, e, dt[2]);
          dt[3] = fmaf(x.w, e, dt[3]);
        }
#pragma unroll
        for (int j = 0; j < 4; ++j) {
          if (need[j]) {
            const float d2 = x2[j] + se2[k] - 2.0f * dt[j];
            atomicAdd(&bs[k], fmaxf(sqrtf(fmaxf(d2, 0.0f)) - 0.1f, 0.0f));
            atomicAdd(&bc[k], 1.0f);
          }
        }
      }
    }
  }
  __syncthreads();  // bs/bc final

  // --- Fold block result into global accumulators. Fixed-point (x 2^30,
  // exact scaling) + integer atomics => associative => deterministic sum,
  // coherent at device scope WITHOUT any threadfence/L2-writeback.
  if (tid < K_) {
    const unsigned long long q30 =
        (unsigned long long)((double)bs[tid] * SCALE_F + 0.5);
    if (q30) atomicAdd((unsigned long long*)(ws + WS_ASUM) + b * K_ + tid, q30);
    const unsigned int c = (unsigned int)(bc[tid] + 0.5f);
    if (c) atomicAdd((unsigned int*)(ws + WS_ACNT) + b * K_ + tid, c);
  }
  __syncthreads();  // drains vmcnt before barrier: atomics performed
  if (tid == 0)
    is_last = (atomicAdd((int*)ws + WS_CTR, 1) == NTOT_ - 1);
  __syncthreads();
  if (!is_last) return;

  // ================= Finalize (last block only) =================
  __shared__ int scy2[B_ * K_], scx2[B_ * K_];
  __shared__ float sEall[B_ * K_ * D_];
  __shared__ float se2all[B_ * K_];
  __shared__ vfloat4 s4[256];
  __shared__ float ssa[B_], srep[B_], sreg[B_];

  // Attract totals via coherent loads (immune to stale clean L2 lines).
  if (tid < B_ * K_) {
    const unsigned long long s = __hip_atomic_load(
        (unsigned long long*)(ws + WS_ASUM) + tid, __ATOMIC_RELAXED,
        __HIP_MEMORY_SCOPE_AGENT);
    const unsigned int c = __hip_atomic_load(
        (unsigned int*)(ws + WS_ACNT) + tid, __ATOMIC_RELAXED,
        __HIP_MEMORY_SCOPE_AGENT);
    const float sum = (float)((double)s * INV_SCALE);
    float v = sum / fmaxf((float)c - 1.0f, 1.0f);
#pragma unroll
    for (int off = 1; off < K_; off <<= 1) v += __shfl_xor(v, off, 64);
    if ((tid & 15) == 0) ssa[tid >> 4] = v;
  }

  // Re-gather E from the read-only input (L2/LLC-hot) — no cross-block
  // visibility dependence at all.
  if (tid < 2 * K_ * B_) {
    const int v = centers[tid];
    if (tid & 1) scx2[tid >> 1] = v; else scy2[tid >> 1] = v;
  }
  __syncthreads();
  for (int idx = tid; idx < B_ * K_ * D_; idx += 256) {
    const int bk = idx >> 5, d = idx & 31, bb = bk >> 4;
    sEall[idx] =
        outp[(((size_t)bb * D_ + d) * H_ + scy2[bk]) * W_ + scx2[bk]];
  }
  __syncthreads();
  if (tid < B_ * K_) {
    float s = 0.0f;
#pragma unroll 8
    for (int d = 0; d < D_; ++d)
      s = fmaf(sEall[tid * D_ + d], sEall[tid * D_ + d], s);
    se2all[tid] = s;
  }
  __syncthreads();

  // Repulse: all 4 images in one float4 tree.
  {
    const int ii = tid >> 4, jj = tid & 15;
    vfloat4 r;
#pragma unroll
    for (int b2 = 0; b2 < B_; ++b2) {
      float dotv = 0.0f;
#pragma unroll 8
      for (int d = 0; d < D_; ++d)
        dotv = fmaf(sEall[(b2 * K_ + ii) * D_ + d],
                    sEall[(b2 * K_ + jj) * D_ + d], dotv);
      const float d2 = se2all[b2 * K_ + ii] + se2all[b2 * K_ + jj] - 2.0f * dotv;
      r[b2] = fmaxf(1.0f - sqrtf(fmaxf(d2, 0.0f)), 0.0f);  // DELTA_R=1.0
    }
    s4[tid] = r;
  }
  __syncthreads();
  for (int s = 128; s > 0; s >>= 1) {
    if (tid < s) s4[tid] += s4[tid + s];
    __syncthreads();
  }
  if (tid < B_) srep[tid] = s4[0][tid] - (float)K_;

  // Reg: sqrt(|E|^2) summed per b (16-lane butterfly).
  if (tid < B_ * K_) {
    float g = sqrtf(fmaxf(se2all[tid], 0.0f));
#pragma unroll
    for (int off = 1; off < K_; off <<= 1) g += __shfl_xor(g, off, 64);
    if ((tid & 15) == 0) sreg[tid >> 4] = g;
  }
  __syncthreads();

  if (tid == 0) {
    float att = 0.0f, rep = 0.0f, reg = 0.0f;
    for (int b2 = 0; b2 < B_; ++b2) {
      att = (att + ssa[b2]) / (float)K_;
      rep = (rep + srep[b2]) / (float)(K_ * (K_ - 1));
      reg = (reg + sreg[b2]) / (float)K_;
    }
    out[0] = att + rep + 0.001f * reg;  // ALPHA=BETA=1, GAMMA=0.001
    out[1] = att;
    out[2] = rep;
  }
}

extern "C" void kernel_launch(void* const* d_in, const int* in_sizes, int n_in,
                              void* d_out, int out_size, void* d_ws, size_t ws_size,
                              hipStream_t stream) {
  const float* outp = (const float*)d_in[0];
  const int* target = (const int*)d_in[1];
  const int* centers = (const int*)d_in[2];
  float* ws = (float*)d_ws;
  float* out = (float*)d_out;

  zero_kernel<<<1, 64, 0, stream>>>(ws);
  attract_kernel<<<dim3(NBLK_, B_), 256, 0, stream>>>(outp, target, centers, ws, out);
}

// Round 7
// 201.013 us; speedup vs baseline: 1.0275x; 1.0275x over previous
//
#include <hip/hip_runtime.h>
#include <hip/hip_bf16.h>

// Problem constants (fixed by setup_inputs): B=4, D=32, H=512, W=512, K=16
#define B_ 4
#define D_ 32
#define H_ 512
#define W_ 512
#define K_ 16
#define N_ (H_ * W_)    // 262144 pixels per image
#define NQ_ (N_ / 4)    // 65536 float4-quads per image
#define NBLK_ 256       // attract blocks per image (256 blk * 256 thr * 4 px = N_)
#define EPAD 33         // sE row pad: bank=(k*33+d)%32 distinct for distinct k

// Workspace layout (float indices):
#define WS_SUM  0      // [64]  sum[b][k]   (written by reduce_kernel)
#define WS_CNT  64     // [64]  cnt[b][k]
#define WS_E2   128    // [64]  |E_k|^2
#define WS_LAB  192    // [64]  label at center (int32 reinterpret)
#define WS_E    264    // [2048] E[b][k][d]
#define WS_PART 4096   // [B*NBLK*32] per-block partials: [b][blk][k]=sum, [16+k]=cnt

typedef float vfloat4 __attribute__((ext_vector_type(4)));
typedef int vint4 __attribute__((ext_vector_type(4)));

__device__ inline vfloat4 nt_load_f4(const float* p) {
  return __builtin_nontemporal_load((const vfloat4*)p);
}
__device__ inline vint4 nt_load_i4(const int* p) {
  return __builtin_nontemporal_load((const vint4*)p);
}

__global__ __launch_bounds__(64) void setup_kernel(
    const float* __restrict__ outp, const int* __restrict__ target,
    const int* __restrict__ centers, float* __restrict__ ws) {
  const int b = blockIdx.x, k = blockIdx.y;
  const int lane = threadIdx.x;
  const int cy = centers[(b * K_ + k) * 2 + 0];
  const int cx = centers[(b * K_ + k) * 2 + 1];
  float v = 0.0f;
  if (lane < D_) {
    v = outp[(((size_t)b * D_ + lane) * H_ + cy) * W_ + cx];
    ws[WS_E + (b * K_ + k) * D_ + lane] = v;
  }
  float s = v * v;
  for (int off = 32; off > 0; off >>= 1) s += __shfl_xor(s, off, 64);
  if (lane == 0) {
    ws[WS_E2 + b * K_ + k] = s;
    ((int*)ws)[WS_LAB + b * K_ + k] = target[(size_t)b * N_ + cy * W_ + cx];
  }
}

__global__ __launch_bounds__(256) void attract_kernel(
    const float* __restrict__ outp, const int* __restrict__ target,
    float* __restrict__ ws) {
  const int b = blockIdx.y;
  const int tid = threadIdx.x;
  __shared__ float sE[K_ * EPAD];
  __shared__ float se2[K_];
  __shared__ int slab[K_];
  __shared__ float bs[K_];
  __shared__ float bc[K_];

  // Stage E via float4 (d runs in groups of 4 within a k-row; pad between rows).
  if (tid < 128) {
    const vfloat4 v = *(const vfloat4*)(ws + WS_E + b * (K_ * D_) + tid * 4);
    const int k = tid >> 3, d = (tid & 7) * 4;
    sE[k * EPAD + d + 0] = v.x;
    sE[k * EPAD + d + 1] = v.y;
    sE[k * EPAD + d + 2] = v.z;
    sE[k * EPAD + d + 3] = v.w;
  }
  if (tid < K_) {
    se2[tid] = ws[WS_E2 + b * K_ + tid];
    slab[tid] = ((const int*)ws)[WS_LAB + b * K_ + tid];
    bs[tid] = 0.0f;
    bc[tid] = 0.0f;
  }
  __syncthreads();

  // One float4-quad of pixels per thread.
  const int q = blockIdx.x * 256 + tid;  // [0, NQ_)
  const float* xb = outp + (size_t)b * D_ * N_;
  const vint4 lab4 = nt_load_i4(target + (size_t)b * N_ + 4 * q);
  const int labv[4] = {lab4.x, lab4.y, lab4.z, lab4.w};

  int kf[4], nm[4];
#pragma unroll
  for (int j = 0; j < 4; ++j) { kf[j] = 0; nm[j] = 0; }
#pragma unroll
  for (int k = 0; k < K_; ++k) {
    const int lk = slab[k];
#pragma unroll
    for (int j = 0; j < 4; ++j) {
      if (labv[j] == lk) { if (nm[j] == 0) kf[j] = k; nm[j]++; }
    }
  }

  float dot[4] = {0.f, 0.f, 0.f, 0.f};
  float x2[4] = {0.f, 0.f, 0.f, 0.f};
#pragma unroll
  for (int d = 0; d < D_; ++d) {
    const vfloat4 x = nt_load_f4(xb + (size_t)d * N_ + 4 * q);
    const float xs[4] = {x.x, x.y, x.z, x.w};
#pragma unroll
    for (int j = 0; j < 4; ++j) {
      const float e = sE[kf[j] * EPAD + d];
      dot[j] = fmaf(xs[j], e, dot[j]);
      x2[j] = fmaf(xs[j], xs[j], x2[j]);
    }
  }

  float hv[4];
#pragma unroll
  for (int j = 0; j < 4; ++j) {
    const float d2 = x2[j] + se2[kf[j]] - 2.0f * dot[j];
    const float h = fmaxf(sqrtf(fmaxf(d2, 0.0f)) - 0.1f, 0.0f);  // DELTA_A=0.1
    hv[j] = (nm[j] > 0) ? h : 0.0f;
  }
  const bool same = (kf[0] == kf[1]) & (kf[1] == kf[2]) & (kf[2] == kf[3]);
  if (same) {  // common case: lane's 4 consecutive pixels share a label
    const float cs = (float)((nm[0] > 0) + (nm[1] > 0) + (nm[2] > 0) + (nm[3] > 0));
    if (cs > 0.0f) {
      atomicAdd(&bs[kf[0]], hv[0] + hv[1] + hv[2] + hv[3]);
      atomicAdd(&bc[kf[0]], cs);
    }
  } else {
#pragma unroll
    for (int j = 0; j < 4; ++j) {
      if (nm[j] > 0) {
        atomicAdd(&bs[kf[j]], hv[j]);
        atomicAdd(&bc[kf[j]], 1.0f);
      }
    }
  }

  // Rare general case: duplicate-label centers (never taken on this input).
  const bool extra = (nm[0] > 1) | (nm[1] > 1) | (nm[2] > 1) | (nm[3] > 1);
  if (__any(extra)) {
    for (int k = 0; k < K_; ++k) {
      bool need[4]; bool anyn = false;
#pragma unroll
      for (int j = 0; j < 4; ++j) {
        need[j] = (nm[j] > 1) && (labv[j] == slab[k]) && (k != kf[j]);
        anyn |= need[j];
      }
      if (__any(anyn)) {
        float dt[4] = {0.f, 0.f, 0.f, 0.f};
        for (int d = 0; d < D_; ++d) {
          const vfloat4 x = nt_load_f4(xb + (size_t)d * N_ + 4 * q);
          const float e = sE[k * EPAD + d];
          dt[0] = fmaf(x.x, e, dt[0]);
          dt[1] = fmaf(x.y, e, dt[1]);
          dt[2] = fmaf(x.z, e, dt[2]);
          dt[3] = fmaf(x.w, e, dt[3]);
        }
#pragma unroll
        for (int j = 0; j < 4; ++j) {
          if (need[j]) {
            const float d2 = x2[j] + se2[k] - 2.0f * dt[j];
            atomicAdd(&bs[k], fmaxf(sqrtf(fmaxf(d2, 0.0f)) - 0.1f, 0.0f));
            atomicAdd(&bc[k], 1.0f);
          }
        }
      }
    }
  }
  __syncthreads();

  if (tid < 2 * K_) {
    float* p = ws + WS_PART + ((size_t)b * NBLK_ + blockIdx.x) * (2 * K_);
    p[tid] = (tid < K_) ? bs[tid] : bc[tid - K_];
  }
}

__global__ __launch_bounds__(256) void reduce_kernel(const float* __restrict__ ws_in,
                                                     float* __restrict__ ws) {
  // One block per (b, k); sums NBLK_ partials deterministically.
  const int b = blockIdx.x >> 4, k = blockIdx.x & 15;
  const int tid = threadIdx.x;
  const float* base = ws_in + WS_PART + (size_t)b * NBLK_ * (2 * K_);
  float s = 0.0f, c = 0.0f;
  for (int i = tid; i < NBLK_; i += 256) {
    s += base[i * (2 * K_) + k];
    c += base[i * (2 * K_) + K_ + k];
  }
  for (int off = 32; off > 0; off >>= 1) {
    s += __shfl_xor(s, off, 64);
    c += __shfl_xor(c, off, 64);
  }
  __shared__ float rs[4], rc[4];
  if ((tid & 63) == 0) { rs[tid >> 6] = s; rc[tid >> 6] = c; }
  __syncthreads();
  if (tid == 0) {
    ws[WS_SUM + b * K_ + k] = rs[0] + rs[1] + rs[2] + rs[3];
    ws[WS_CNT + b * K_ + k] = rc[0] + rc[1] + rc[2] + rc[3];
  }
}

__global__ __launch_bounds__(256) void final_kernel(const float* __restrict__ ws,
                                                    float* __restrict__ out) {
  __shared__ float sE[B_ * K_ * D_];
  __shared__ float sred[256];
  __shared__ float srep[B_];
  __shared__ float sreg[B_];
  __shared__ float ssa[B_];
  const int tid = threadIdx.x;
  for (int i = tid; i < B_ * K_ * D_; i += 256) sE[i] = ws[WS_E + i];
  __syncthreads();

  // Repulse: 256 pairs per image, tree-reduce per b.
  const int i = tid >> 4, j = tid & 15;
  for (int b = 0; b < B_; ++b) {
    float dotv = 0.0f;
#pragma unroll 8
    for (int d = 0; d < D_; ++d)
      dotv = fmaf(sE[(b * K_ + i) * D_ + d], sE[(b * K_ + j) * D_ + d], dotv);
    const float d2 = ws[WS_E2 + b * K_ + i] + ws[WS_E2 + b * K_ + j] - 2.0f * dotv;
    sred[tid] = fmaxf(1.0f - sqrtf(fmaxf(d2, 0.0f)), 0.0f);  // DELTA_R=1.0
    __syncthreads();
    for (int s = 128; s > 0; s >>= 1) {
      if (tid < s) sred[tid] += sred[tid + s];
      __syncthreads();
    }
    if (tid == 0) srep[b] = sred[0] - (float)K_;
    __syncthreads();
  }

  // Reg: sqrt(|E|^2) summed per b.
  sred[tid] = (tid < B_ * K_) ? sqrtf(fmaxf(ws[WS_E2 + tid], 0.0f)) : 0.0f;
  __syncthreads();
  if (tid < B_) {
    float s = 0.0f;
    for (int k = 0; k < K_; ++k) s += sred[tid * K_ + k];
    sreg[tid] = s;
  }

  // Attract per-b sums: tid<64 = (b,k); butterfly over k bits (16-aligned, safe).
  if (tid < B_ * K_) {
    const float c = ws[WS_CNT + tid];
    float v = ws[WS_SUM + tid] / fmaxf(c - 1.0f, 1.0f);
    for (int off = 1; off < K_; off <<= 1) v += __shfl_xor(v, off, 64);
    if ((tid & 15) == 0) ssa[tid >> 4] = v;
  }
  __syncthreads();

  if (tid == 0) {
    float att = 0.0f, rep = 0.0f, reg = 0.0f;
    for (int b = 0; b < B_; ++b) {
      att = (att + ssa[b]) / (float)K_;
      rep = (rep + srep[b]) / (float)(K_ * (K_ - 1));
      reg = (reg + sreg[b]) / (float)K_;
    }
    out[0] = att + rep + 0.001f * reg;  // ALPHA=BETA=1, GAMMA=0.001
    out[1] = att;
    out[2] = rep;
  }
}

extern "C" void kernel_launch(void* const* d_in, const int* in_sizes, int n_in,
                              void* d_out, int out_size, void* d_ws, size_t ws_size,
                              hipStream_t stream) {
  const float* outp = (const float*)d_in[0];
  const int* target = (const int*)d_in[1];
  const int* centers = (const int*)d_in[2];
  float* ws = (float*)d_ws;
  float* out = (float*)d_out;

  setup_kernel<<<dim3(B_, K_), 64, 0, stream>>>(outp, target, centers, ws);
  attract_kernel<<<dim3(NBLK_, B_), 256, 0, stream>>>(outp, target, ws);
  reduce_kernel<<<dim3(B_ * K_), 256, 0, stream>>>(ws, ws);
  final_kernel<<<1, 256, 0, stream>>>(ws, out);
}